// Round 11
// baseline (239.702 us; speedup 1.0000x reference)
//
#include <hip/hip_runtime.h>

#define IN_FEAT 1024
#define OUT_FEAT 1024
#define NSAMP 8192
#define KBASE 1024
#define KSPL 8192
// fp6 tiled layout (B only now): [rowblk(128)][kb(64)][quad(4)][row(128)][24B]
#define GRANB 24
#define KBBYTES (4 * 128 * GRANB)    /* 12288 B */
#define RBSTRIDE (64L * KBBYTES)     /* 786432 B */

typedef __bf16 v8bf __attribute__((ext_vector_type(8)));
typedef float v4f __attribute__((ext_vector_type(4)));
typedef float v32f __attribute__((ext_vector_type(32)));
typedef int v8i __attribute__((ext_vector_type(8)));
typedef int v6i __attribute__((ext_vector_type(6)));
typedef unsigned long long u64;

__device__ __forceinline__ void load16_lds(const void* g, void* l) {
  __builtin_amdgcn_global_load_lds(
      (const __attribute__((address_space(1))) void*)g,
      (__attribute__((address_space(3))) void*)l, 16, 0, 0);
}

// fp6 e2m3 encode (round-nearest)
__device__ __forceinline__ unsigned enc_e2m3(float v) {
  unsigned s = 0u;
  float a = v;
  if (a < 0.f) { s = 32u; a = -a; }
  unsigned code;
  if (a < 1.9375f)      code = (unsigned)rintf(a * 8.0f);
  else if (a < 3.875f)  code = 16u + (unsigned)rintf((a - 2.0f) * 4.0f);
  else if (a < 7.25f)   code = 24u + (unsigned)rintf((a - 4.0f) * 2.0f);
  else                  code = 31u;
  return s | code;
}

__device__ __forceinline__ void pack32_fp6(const float* vals, unsigned char* dst) {
#if __has_builtin(__builtin_amdgcn_cvt_scalef32_pk32_fp6_f32)
  v32f v;
#pragma unroll
  for (int e = 0; e < 32; ++e) v[e] = vals[e];
  v6i r = __builtin_amdgcn_cvt_scalef32_pk32_fp6_f32(v, 1.0f);
  u64* dq = reinterpret_cast<u64*>(dst);
  dq[0] = (u64)(unsigned)r[0] | ((u64)(unsigned)r[1] << 32);
  dq[1] = (u64)(unsigned)r[2] | ((u64)(unsigned)r[3] << 32);
  dq[2] = (u64)(unsigned)r[4] | ((u64)(unsigned)r[5] << 32);
#else
  u64 w0 = 0, w1 = 0, w2 = 0;
#pragma unroll
  for (int e = 0; e < 32; ++e) {
    u64 c = enc_e2m3(vals[e]);
    int bp = 6 * e;
    if (bp < 64) {
      w0 |= c << bp;
      if (bp > 58) w1 |= c >> (64 - bp);
    } else if (bp < 128) {
      w1 |= c << (bp - 64);
      if (bp > 122) w2 |= c >> (128 - bp);
    } else {
      w2 |= c << (bp - 128);
    }
  }
  u64* dq = reinterpret_cast<u64*>(dst);
  dq[0] = w0; dq[1] = w1; dq[2] = w2;
#endif
}

// B-side builder only (A is generated on the fly inside the GEMM).
// B1[o,i]=bw bf16; B2 = fp6-tiled sw*sc*256.
__global__ __launch_bounds__(256) void build_B(const float* __restrict__ bw,
                                               const float* __restrict__ sw,
                                               const float* __restrict__ sc,
                                               __bf16* __restrict__ B1,
                                               unsigned char* __restrict__ B2) {
  int g = blockIdx.x * 256 + threadIdx.x;
  int r = g & 127;
  int quad = (g >> 7) & 3;
  int kb = (g >> 9) & 63;
  int ob = g >> 15;
  long o = ob * 128 + r;
  int i0 = kb * 16 + quad * 4;

  float4 bw4 = *reinterpret_cast<const float4*>(bw + o * IN_FEAT + i0);
  union { __bf16 h[4]; u64 u; } b1;
  b1.h[0] = (__bf16)bw4.x; b1.h[1] = (__bf16)bw4.y;
  b1.h[2] = (__bf16)bw4.z; b1.h[3] = (__bf16)bw4.w;
  *reinterpret_cast<u64*>(B1 + o * IN_FEAT + i0) = b1.u;

  float vals[32];
  float4 sc4 = *reinterpret_cast<const float4*>(sc + o * IN_FEAT + i0);
  float scs[4] = {sc4.x, sc4.y, sc4.z, sc4.w};
#pragma unroll
  for (int j = 0; j < 4; ++j) {
    float scale = scs[j] * 256.0f; // 2^8, undone by scaleB=119
    const float4* sp =
        reinterpret_cast<const float4*>(sw + (o * IN_FEAT + i0 + j) * 8);
    float4 p0 = sp[0];
    float4 p1 = sp[1];
    vals[j * 8 + 0] = p0.x * scale; vals[j * 8 + 1] = p0.y * scale;
    vals[j * 8 + 2] = p0.z * scale; vals[j * 8 + 3] = p0.w * scale;
    vals[j * 8 + 4] = p1.x * scale; vals[j * 8 + 5] = p1.y * scale;
    vals[j * 8 + 6] = p1.z * scale; vals[j * 8 + 7] = p1.w * scale;
  }
  pack32_fp6(vals, B2 + (long)ob * RBSTRIDE + kb * KBBYTES +
                       quad * (128 * GRANB) + r * GRANB);
}

// Fused GEMM with on-the-fly A: 128x128 tile, BK=256, 32 iterations.
// Per iter, thread t (r=t&127, half=t>>7) loads x[bm*128+r, it*32+half*16 ..
// +15] (64B = one full cache line per lane), computes 16 silu -> As1 and 4
// fp6 granules via the u-LUT -> As6 (thread mapping gives quad=j, kb2=half
// exactly covering the fragment layout). B staged via global_load_lds as
// before. Eliminates the A-materialization round-trip (~117 MB + a
// dispatch); the ~300 VALU ops/thread/iter hide in the barrier-drain idle
// (m114 MFMA/VALU co-scheduling).
__global__ __launch_bounds__(256, 2) void gemm_fused(const float* __restrict__ x,
                                                     const unsigned char* __restrict__ B2,
                                                     const __bf16* __restrict__ B1,
                                                     float* __restrict__ C) {
  __shared__ __attribute__((aligned(16))) unsigned char smem[65536];
  unsigned char* As6 = smem;                               // 24 KB (2 kb)
  unsigned char* Bs6 = smem + 24576;                       // 24 KB
  __bf16* As1 = reinterpret_cast<__bf16*>(smem + 49152);   // 8 KB
  __bf16* Bs1 = reinterpret_cast<__bf16*>(smem + 57344);   // 8 KB
  __shared__ unsigned lut[256];

  const int tid = threadIdx.x;
  const int bm = blockIdx.x;
  const int bn = blockIdx.y;

  // u-LUT: entry e holds the 4 consecutive nonzero cubic-basis fp6 codes
  // (x4 prescale) for u=(e+.5)/256, packed 4x6b.
  {
    float u = ((float)tid + 0.5f) * (1.0f / 256.0f);
    float u2 = u * u, u3 = u2 * u;
    float om = 1.0f - u;
    const float s = 4.0f / 6.0f;
    unsigned c0 = enc_e2m3(om * om * om * s);
    unsigned c1 = enc_e2m3((3.f * u3 - 6.f * u2 + 4.f) * s);
    unsigned c2 = enc_e2m3((-3.f * u3 + 3.f * u2 + 3.f * u + 1.f) * s);
    unsigned c3 = enc_e2m3(u3 * s);
    lut[tid] = c0 | (c1 << 6) | (c2 << 12) | (c3 << 18);
  }

  const int lane = tid & 63;
  const int w = tid >> 6;
  const int wm = (w >> 1) * 64;
  const int wn = (w & 1) * 64;
  const int l16 = lane & 15;
  const int quad = lane >> 4;
  const int r = tid & 127;
  const int half = tid >> 7;

  // staging pointers
  const unsigned char* gB6 = B2 + (long)bn * RBSTRIDE + tid * 16;
  const int c0 = tid, c1 = tid + 256;
  const __bf16* gB1_0 = B1 + (long)(bn * 128 + (c0 >> 2)) * KBASE + (c0 & 3) * 8;
  const __bf16* gB1_1 = B1 + (long)(bn * 128 + (c1 >> 2)) * KBASE + (c1 & 3) * 8;
  const float* gx = x + (long)(bm * 128 + r) * IN_FEAT + half * 16;

  // A-write pointers (this thread's slots in the fragment layout)
  unsigned char* aW6 = As6 + half * KBBYTES + r * GRANB; // + j*3072
  __bf16* aW1 = As1 + r * 32 + half * 16;

  // fragment pointers
  const unsigned char* aF6 = As6 + quad * (128 * GRANB) + (wm + l16) * GRANB;
  const unsigned char* bF6 = Bs6 + quad * (128 * GRANB) + (wn + l16) * GRANB;
  const __bf16* aF1 = As1 + (wm + l16) * 32 + quad * 8;
  const __bf16* bF1 = Bs1 + (wn + l16) * 32 + quad * 8;

  v4f acc[4][4] = {};

  float4 xq[4], xqn[4];
#pragma unroll
  for (int j = 0; j < 4; ++j)
    xq[j] = *reinterpret_cast<const float4*>(gx + j * 4);

  __syncthreads(); // lut ready

  for (int it = 0; it < 32; ++it) {
    // --- B staging (DMA) ---
    const long off6 = (long)it * (2 * KBBYTES);
#pragma unroll
    for (int t = 0; t < 6; ++t)
      load16_lds(gB6 + off6 + t * 4096, &Bs6[tid * 16 + t * 4096]);
    const int k0 = it * 32;
    load16_lds(gB1_0 + k0, &Bs1[c0 * 8]);
    load16_lds(gB1_1 + k0, &Bs1[c1 * 8]);

    // --- A generation from registers ---
    {
      // silu -> As1 (16 bf16 = 2x16B)
      union { __bf16 h[8]; uint4 q; } s0, s1;
#pragma unroll
      for (int j = 0; j < 4; ++j) {
        float vv[4] = {xq[j].x, xq[j].y, xq[j].z, xq[j].w};
#pragma unroll
        for (int e = 0; e < 4; ++e) {
          float v = vv[e];
          __bf16 sv = (__bf16)(v / (1.0f + __expf(-v)));
          if (j < 2) s0.h[j * 4 + e] = sv; else s1.h[(j - 2) * 4 + e] = sv;
        }
      }
      *reinterpret_cast<uint4*>(aW1) = s0.q;
      *reinterpret_cast<uint4*>(aW1 + 8) = s1.q;

      // fp6 granules -> As6 (quad=j, kb2=half)
#pragma unroll
      for (int j = 0; j < 4; ++j) {
        float vv[4] = {xq[j].x, xq[j].y, xq[j].z, xq[j].w};
        u64 w0 = 0, w1 = 0, w2 = 0;
#pragma unroll
        for (int e = 0; e < 4; ++e) {
          float p = (vv[e] + 2.2f) * 2.5f;
          float fl = floorf(p);
          int t0 = (int)fl;
          int idx = (int)((p - fl) * 256.0f) & 255;
          u64 codes = (u64)lut[idx];
          int sh = 6 * t0 - 18;
          u64 seg = (sh >= 0) ? (codes << sh) : (codes >> (-sh));
          seg = ((unsigned)t0 <= 10u) ? (seg & 0xFFFFFFFFFFFFULL) : 0ULL;
          if (e == 0) w0 |= seg;
          else if (e == 1) { w0 |= seg << 48; w1 |= seg >> 16; }
          else if (e == 2) { w1 |= seg << 32; w2 |= seg >> 32; }
          else             { w2 |= seg << 16; }
        }
        u64* dq = reinterpret_cast<u64*>(aW6 + j * 3072);
        dq[0] = w0; dq[1] = w1; dq[2] = w2;
      }
    }

    // --- prefetch next x ---
    if (it < 31) {
#pragma unroll
      for (int j = 0; j < 4; ++j)
        xqn[j] = *reinterpret_cast<const float4*>(gx + (it + 1) * 32 + j * 4);
    }

    __syncthreads();

    // --- fp6 MFMAs: two k-blocks x (4 mi x 4 ni) ---
#pragma unroll
    for (int kb2 = 0; kb2 < 2; ++kb2) {
      const unsigned char* aB = aF6 + kb2 * KBBYTES;
      const unsigned char* bB = bF6 + kb2 * KBBYTES;
      v8i af[4], bfr[4];
#pragma unroll
      for (int mi = 0; mi < 4; ++mi) {
        const unsigned char* rb = aB + mi * 16 * GRANB;
        u64 a0 = *reinterpret_cast<const u64*>(rb);
        u64 a1 = *reinterpret_cast<const u64*>(rb + 8);
        u64 a2 = *reinterpret_cast<const u64*>(rb + 16);
        v8i f = {(int)a0, (int)(a0 >> 32), (int)a1, (int)(a1 >> 32),
                 (int)a2, (int)(a2 >> 32), 0, 0};
        af[mi] = f;
      }
#pragma unroll
      for (int ni = 0; ni < 4; ++ni) {
        const unsigned char* rb = bB + ni * 16 * GRANB;
        u64 b0 = *reinterpret_cast<const u64*>(rb);
        u64 b1 = *reinterpret_cast<const u64*>(rb + 8);
        u64 b2 = *reinterpret_cast<const u64*>(rb + 16);
        v8i f = {(int)b0, (int)(b0 >> 32), (int)b1, (int)(b1 >> 32),
                 (int)b2, (int)(b2 >> 32), 0, 0};
        bfr[ni] = f;
      }
#pragma unroll
      for (int mi = 0; mi < 4; ++mi)
#pragma unroll
        for (int ni = 0; ni < 4; ++ni)
          // fmt 2 = fp6 e2m3 both; scaleA=125 (2^-2), scaleB=119 (2^-8)
          acc[mi][ni] = __builtin_amdgcn_mfma_scale_f32_16x16x128_f8f6f4(
              af[mi], bfr[ni], acc[mi][ni], 2, 2, 0, 125, 0, 119);
    }
    // --- bf16 MFMAs ---
    {
      v8bf af[4], bfr[4];
#pragma unroll
      for (int t = 0; t < 4; ++t)
        af[t] = *reinterpret_cast<const v8bf*>(aF1 + t * 16 * 32);
#pragma unroll
      for (int t = 0; t < 4; ++t)
        bfr[t] = *reinterpret_cast<const v8bf*>(bF1 + t * 16 * 32);
#pragma unroll
      for (int mi = 0; mi < 4; ++mi)
#pragma unroll
        for (int ni = 0; ni < 4; ++ni)
          acc[mi][ni] = __builtin_amdgcn_mfma_f32_16x16x32_bf16(
              af[mi], bfr[ni], acc[mi][ni], 0, 0, 0);
    }
    __syncthreads();

#pragma unroll
    for (int j = 0; j < 4; ++j) xq[j] = xqn[j];
  }

  // Epilogue: C/D layout col = lane&15, row = quad*4 + reg. Single write.
#pragma unroll
  for (int mi = 0; mi < 4; ++mi)
#pragma unroll
    for (int ni = 0; ni < 4; ++ni)
#pragma unroll
      for (int rr = 0; rr < 4; ++rr) {
        int row = bm * 128 + wm + mi * 16 + quad * 4 + rr;
        int col = bn * 128 + wn + ni * 16 + l16;
        C[(long)row * OUT_FEAT + col] = acc[mi][ni][rr];
      }
}

extern "C" void kernel_launch(void* const* d_in, const int* in_sizes, int n_in,
                              void* d_out, int out_size, void* d_ws, size_t ws_size,
                              hipStream_t stream) {
  const float* x = (const float*)d_in[0];
  const float* bw = (const float*)d_in[1];
  const float* sw = (const float*)d_in[2];
  const float* sc = (const float*)d_in[3];
  float* out = (float*)d_out;

  // ws: B1 bf16 2MB | B2 fp6 6.3MB  (A is generated on the fly in the GEMM)
  __bf16* B1 = (__bf16*)d_ws;
  unsigned char* B2 = (unsigned char*)(B1 + (size_t)OUT_FEAT * KBASE);

  build_B<<<1024, 256, 0, stream>>>(bw, sw, sc, B1, B2);
  gemm_fused<<<dim3(NSAMP / 128, OUT_FEAT / 128), 256, 0, stream>>>(
      x, B2, B1, out);
}